// Round 4
// baseline (2119.869 us; speedup 1.0000x reference)
//
#include <hip/hip_runtime.h>

#define N 8192
#define D 512
#define KNN 15
#define NPAIR 105
#define EPSF 1e-8f

#define RB 32
#define CB 64
#define KB 32

#define INF __int_as_float(0x7f800000)

typedef __attribute__((ext_vector_type(4))) float f32x4;
typedef __attribute__((ext_vector_type(8))) short s16x8;
typedef __attribute__((ext_vector_type(8))) unsigned short u16x8;
typedef unsigned long long u64;

typedef const unsigned int __attribute__((address_space(1)))* gp_t;
typedef unsigned int __attribute__((address_space(3)))* lp_t;

__device__ __forceinline__ void gl_lds16(const void* g, void* l) {
  __builtin_amdgcn_global_load_lds((gp_t)g, (lp_t)l, 16, 0, 0);
}

__device__ __forceinline__ unsigned short bf16_rne(float x) {
  unsigned int u = __float_as_uint(x);
  return (unsigned short)((u + 0x7fffu + ((u >> 16) & 1u)) >> 16);
}

// ---------------------------------------------------------------- sq norms
__global__ __launch_bounds__(256)
void k_sqnorm(const float* __restrict__ A, const float* __restrict__ B,
              float* __restrict__ sq)
{
  int tid = threadIdx.x;
  int lane = tid & 63;
  int row = blockIdx.x * 4 + (tid >> 6);          // 0 .. 2N-1
  const float* src = (row < N) ? (A + (size_t)row * D)
                               : (B + (size_t)(row - N) * D);
  const float4* s4 = (const float4*)src + lane * 2;
  float4 x0 = s4[0], x1 = s4[1];
  float s = x0.x*x0.x + x0.y*x0.y + x0.z*x0.z + x0.w*x0.w
          + x1.x*x1.x + x1.y*x1.y + x1.z*x1.z + x1.w*x1.w;
#pragma unroll
  for (int o = 32; o; o >>= 1) s += __shfl_xor(s, o);
  if (lane == 0) sq[row] = s;
}

// ---------------------------------------------------------------- bf16 hi/lo split
__global__ __launch_bounds__(256)
void k_split(const float* __restrict__ A, const float* __restrict__ B,
             unsigned short* __restrict__ hi, unsigned short* __restrict__ lo)
{
  size_t t = (size_t)blockIdx.x * 256 + threadIdx.x;
  size_t base = t * 8;
  const float* src = (base < (size_t)N * D) ? (A + base) : (B + (base - (size_t)N * D));
  float4 x0 = ((const float4*)src)[0];
  float4 x1 = ((const float4*)src)[1];
  float xs[8] = {x0.x, x0.y, x0.z, x0.w, x1.x, x1.y, x1.z, x1.w};
  u16x8 hv, lv;
#pragma unroll
  for (int j = 0; j < 8; ++j) {
    unsigned short h = bf16_rne(xs[j]);
    float hf = __uint_as_float(((unsigned int)h) << 16);
    hv[j] = h;
    lv[j] = bf16_rne(xs[j] - hf);
  }
  *(u16x8*)(hi + base) = hv;
  *(u16x8*)(lo + base) = lv;
}

// ================================================================ SYM path
// one 128x128 tile per block, upper-triangle only; row-scan + col-scan;
// u64 (d2bits<<32|idx) partial top-15 per (row, split) into pbuf (one matrix).
__global__ __launch_bounds__(256)
void k_sym(const unsigned short* __restrict__ hi, const unsigned short* __restrict__ lo,
           const float* __restrict__ sqall, u64* __restrict__ pbuf, int mat)
{
  const int bi = blockIdx.x, bj = blockIdx.y;
  if (bj < bi) return;

  __shared__ __align__(16) char smem[33792];
  // staging layout (bytes): Ahi [0,8192) Alo [8192,16384) Bhi [16384,24576) Blo [24576,32768)
  short* Ahi = (short*)smem;
  float* Dt = (float*)smem;        // [128][66] overlay (row phase)
  float* Dv = (float*)smem;        // [64][130] overlay (col phase)
  u64*  SU  = (u64*)smem;          // [128][30] overlay (merge)

  const int tid = threadIdx.x;
  const int lane = tid & 63, w = tid >> 6;
  const int wr = w >> 1, wc = w & 1;
  const int fr = lane & 15, fq = lane >> 4;
  const int sgx = fq ^ ((fr >> 1) & 3);

  const int row0 = bi * 128, col0 = bj * 128;
  const size_t mbase = (size_t)mat * N * D;
  const unsigned short* Hi = hi + mbase;
  const unsigned short* Lo = lo + mbase;
  const float* sq = sqall + mat * N;

  // staging source pointers (per-lane), dest bases wave-uniform
  const int sr_ = tid >> 2, sseg = tid & 3;
  const int ssg = sseg ^ ((sr_ >> 1) & 3);
  const unsigned short* pAh = Hi + (size_t)(row0 + sr_) * D + ssg * 8;
  const unsigned short* pAl = Lo + (size_t)(row0 + sr_) * D + ssg * 8;
  const unsigned short* pBh = Hi + (size_t)(col0 + sr_) * D + ssg * 8;
  const unsigned short* pBl = Lo + (size_t)(col0 + sr_) * D + ssg * 8;
  char* dA = smem + (w << 10);

  float sqr[4][4];
#pragma unroll
  for (int m = 0; m < 4; ++m)
#pragma unroll
    for (int j = 0; j < 4; ++j)
      sqr[m][j] = sq[row0 + wr * 64 + m * 16 + fq * 4 + j];
  float sqc[4];
#pragma unroll
  for (int n = 0; n < 4; ++n) sqc[n] = sq[col0 + wc * 64 + n * 16 + fr];

  f32x4 acc[4][4];
#pragma unroll
  for (int m = 0; m < 4; ++m)
#pragma unroll
    for (int n = 0; n < 4; ++n) acc[m][n] = (f32x4){0.f, 0.f, 0.f, 0.f};

  for (int kt = 0; kt < 16; ++kt) {
    gl_lds16(pAh, dA);
    gl_lds16((const char*)pAh + 65536, dA + 4096);
    gl_lds16(pAl, dA + 8192);
    gl_lds16((const char*)pAl + 65536, dA + 12288);
    gl_lds16(pBh, dA + 16384);
    gl_lds16((const char*)pBh + 65536, dA + 20480);
    gl_lds16(pBl, dA + 24576);
    gl_lds16((const char*)pBl + 65536, dA + 28672);
    pAh += 32; pAl += 32; pBh += 32; pBl += 32;
    __syncthreads();

    s16x8 ah[4], al[4], bh[4], bl[4];
#pragma unroll
    for (int m = 0; m < 4; ++m) {
      const int off = (wr * 64 + m * 16 + fr) * 32 + sgx * 8;
      ah[m] = *(const s16x8*)(Ahi + off);
      al[m] = *(const s16x8*)(Ahi + 4096 + off);
    }
#pragma unroll
    for (int n = 0; n < 4; ++n) {
      const int off = (wc * 64 + n * 16 + fr) * 32 + sgx * 8;
      bh[n] = *(const s16x8*)(Ahi + 8192 + off);
      bl[n] = *(const s16x8*)(Ahi + 12288 + off);
    }
#pragma unroll
    for (int m = 0; m < 4; ++m)
#pragma unroll
      for (int n = 0; n < 4; ++n) {
        acc[m][n] = __builtin_amdgcn_mfma_f32_16x16x32_bf16(ah[m], bh[n], acc[m][n], 0, 0, 0);
        acc[m][n] = __builtin_amdgcn_mfma_f32_16x16x32_bf16(ah[m], bl[n], acc[m][n], 0, 0, 0);
        acc[m][n] = __builtin_amdgcn_mfma_f32_16x16x32_bf16(al[m], bh[n], acc[m][n], 0, 0, 0);
      }
    __syncthreads();
  }

  const bool diag = (bi == bj);
  const int srow = tid >> 1, ssub = tid & 1;

  u64 rT[KNN], cT[KNN];
#pragma unroll
  for (int j = 0; j < KNN; ++j) { rT[j] = ~0ull; cT[j] = ~0ull; }

  // ---- row phase: two 64-col halves
#pragma unroll 1
  for (int h = 0; h < 2; ++h) {
    if (wc == h) {
#pragma unroll
      for (int m = 0; m < 4; ++m)
#pragma unroll
        for (int n = 0; n < 4; ++n) {
          const int cl = n * 16 + fr;
          const int rbase = wr * 64 + m * 16 + fq * 4;
#pragma unroll
          for (int j = 0; j < 4; ++j) {
            float d2 = fmaf(-2.0f, acc[m][n][j], sqr[m][j] + sqc[n]);
            if (diag && (rbase + j == h * 64 + cl)) d2 = INF;
            Dt[(rbase + j) * 66 + cl] = d2;
          }
        }
    }
    __syncthreads();
    {
      const unsigned gb = (unsigned)(col0 + h * 64 + ssub * 32);
      u64 kth = rT[KNN - 1];
#pragma unroll 1
      for (int c = 0; c < 32; ++c) {
        const float d2 = Dt[srow * 66 + ssub * 32 + c];
        const u64 key = ((u64)__float_as_uint(d2) << 32) | (gb + c);
        if (key < kth) {
#pragma unroll
          for (int j = KNN - 1; j >= 1; --j) {
            const bool ja = (rT[j] > key), jb = (rT[j - 1] > key);
            rT[j] = jb ? rT[j - 1] : (ja ? key : rT[j]);
          }
          if (rT[0] > key) rT[0] = key;
          kth = rT[KNN - 1];
        }
      }
    }
    __syncthreads();
  }

  // ---- col phase (skip on diag): two 64-row halves, scan columns
  if (!diag) {
#pragma unroll 1
    for (int v = 0; v < 2; ++v) {
      if (wr == v) {
#pragma unroll
        for (int m = 0; m < 4; ++m)
#pragma unroll
          for (int n = 0; n < 4; ++n) {
            const int cl2 = wc * 64 + n * 16 + fr;
            const int rloc = m * 16 + fq * 4;
#pragma unroll
            for (int j = 0; j < 4; ++j) {
              const float d2 = fmaf(-2.0f, acc[m][n][j], sqr[m][j] + sqc[n]);
              Dv[(rloc + j) * 130 + cl2] = d2;
            }
          }
      }
      __syncthreads();
      {
        const int scol = tid >> 1;
        const unsigned gb = (unsigned)(row0 + v * 64 + ssub * 32);
        u64 kth = cT[KNN - 1];
#pragma unroll 1
        for (int rr = 0; rr < 32; ++rr) {
          const float d2 = Dv[(ssub * 32 + rr) * 130 + scol];
          const u64 key = ((u64)__float_as_uint(d2) << 32) | (gb + rr);
          if (key < kth) {
#pragma unroll
            for (int j = KNN - 1; j >= 1; --j) {
              const bool ja = (cT[j] > key), jb = (cT[j - 1] > key);
              cT[j] = jb ? cT[j - 1] : (ja ? key : cT[j]);
            }
            if (cT[0] > key) cT[0] = key;
            kth = cT[KNN - 1];
          }
        }
      }
      __syncthreads();
    }
  }

  // ---- write row-side partials (merge the 2 per-row lists)
#pragma unroll
  for (int j = 0; j < KNN; ++j) SU[srow * 30 + ssub * 15 + j] = rT[j];
  __syncthreads();
  if (tid < 128) {
    const size_t pb = ((size_t)row0 + tid) * 960 + (size_t)bj * 15;
    int p0 = 0, p1 = 0;
#pragma unroll
    for (int j = 0; j < KNN; ++j) {
      const u64 a = (p0 < KNN) ? SU[tid * 30 + p0] : ~0ull;
      const u64 b = (p1 < KNN) ? SU[tid * 30 + 15 + p1] : ~0ull;
      const bool ta = a <= b;
      pbuf[pb + j] = ta ? a : b;
      if (ta) ++p0; else ++p1;
    }
  }
  if (!diag) {
    __syncthreads();
#pragma unroll
    for (int j = 0; j < KNN; ++j) SU[srow * 30 + ssub * 15 + j] = cT[j];
    __syncthreads();
    if (tid < 128) {
      const size_t pb = ((size_t)col0 + tid) * 960 + (size_t)bi * 15;
      int p0 = 0, p1 = 0;
#pragma unroll
      for (int j = 0; j < KNN; ++j) {
        const u64 a = (p0 < KNN) ? SU[tid * 30 + p0] : ~0ull;
        const u64 b = (p1 < KNN) ? SU[tid * 30 + 15 + p1] : ~0ull;
        const bool ta = a <= b;
        pbuf[pb + j] = ta ? a : b;
        if (ta) ++p0; else ++p1;
      }
    }
  }
}

// ---------------------------------------------------------------- 64-split tournament merge (one matrix)
__global__ __launch_bounds__(256)
void k_merge64(const u64* __restrict__ pbuf, float* __restrict__ knnd,
               int* __restrict__ knni, int mat)
{
  const int tid = threadIdx.x;
  const int lane = tid & 63, w = tid >> 6;
  const int row = blockIdx.x * 4 + w;
  const u64* base = pbuf + (size_t)row * 960 + lane * 15;

  int p = 0;
  u64 v = base[0];
  u64 vn = base[1];
  const size_t ob = ((size_t)mat * N + row) * KNN;
#pragma unroll 1
  for (int r = 0; r < KNN; ++r) {
    u64 m = v;
#pragma unroll
    for (int o = 32; o; o >>= 1) {
      const u64 t = __shfl_xor(m, o);
      if (t < m) m = t;
    }
    const bool win = (v == m);
    if (win) {
      ++p;
      v = vn;
      vn = (p + 1 < KNN) ? base[p + 1] : ~0ull;
    }
    if (lane == 0) {
      const float d2v = __uint_as_float((unsigned)(m >> 32));
      knnd[ob + r] = (d2v > 0.f) ? sqrtf(fmaxf(d2v, 1e-24f)) : 0.f;
      knni[ob + r] = (int)(m & 0xffffffffu);
    }
  }
}

// ================================================================ MED path (improved fused 4-split)
__global__ __launch_bounds__(256)
void k_med(const unsigned short* __restrict__ hi, const unsigned short* __restrict__ lo,
           const float* __restrict__ sqall,
           float* __restrict__ pval, int* __restrict__ pidx)
{
  __shared__ __align__(16) char smem[33792];
  short* Ahi = (short*)smem;
  float* Dt = (float*)smem;                 // [128][66] overlay
  float* SV = (float*)smem;                 // [128][30] overlay
  int*   SI = (int*)(smem + 15360);

  const int tid = threadIdx.x;
  const int lane = tid & 63, w = tid >> 6;
  const int wr = w >> 1, wc = w & 1;
  const int fr = lane & 15, fq = lane >> 4;
  const int sgx = fq ^ ((fr >> 1) & 3);

  const int rb = blockIdx.x, split = blockIdx.y, which = blockIdx.z;
  const int row0 = rb * 128;
  const int c0 = split * 2048;
  const size_t mbase = (size_t)which * N * D;
  const unsigned short* Hi = hi + mbase;
  const unsigned short* Lo = lo + mbase;
  const float* sq = sqall + which * N;

  const int sr_ = tid >> 2, sseg = tid & 3;
  const int ssg = sseg ^ ((sr_ >> 1) & 3);
  const unsigned short* pAh = Hi + (size_t)(row0 + sr_) * D + ssg * 8;
  const unsigned short* pAl = Lo + (size_t)(row0 + sr_) * D + ssg * 8;
  const unsigned short* pBh = Hi + (size_t)(c0 + sr_) * D + ssg * 8;
  const unsigned short* pBl = Lo + (size_t)(c0 + sr_) * D + ssg * 8;
  char* dA = smem + (w << 10);

  const int srow = tid >> 1, ssub = tid & 1;
  float tv[KNN]; int ti[KNN];
#pragma unroll
  for (int j = 0; j < KNN; ++j) { tv[j] = INF; ti[j] = -1; }

  float sqr[4][4];
#pragma unroll
  for (int m = 0; m < 4; ++m)
#pragma unroll
    for (int j = 0; j < 4; ++j)
      sqr[m][j] = sq[row0 + wr * 64 + m * 16 + fq * 4 + j];

#pragma unroll 1
  for (int t = 0; t < 16; ++t) {
    const int ct = c0 + t * 128;
    float sqc[4];
#pragma unroll
    for (int n = 0; n < 4; ++n) sqc[n] = sq[ct + wc * 64 + n * 16 + fr];

    f32x4 acc[4][4];
#pragma unroll
    for (int m = 0; m < 4; ++m)
#pragma unroll
      for (int n = 0; n < 4; ++n) acc[m][n] = (f32x4){0.f, 0.f, 0.f, 0.f};

    for (int kt = 0; kt < 16; ++kt) {
      gl_lds16(pAh, dA);
      gl_lds16((const char*)pAh + 65536, dA + 4096);
      gl_lds16(pAl, dA + 8192);
      gl_lds16((const char*)pAl + 65536, dA + 12288);
      gl_lds16(pBh, dA + 16384);
      gl_lds16((const char*)pBh + 65536, dA + 20480);
      gl_lds16(pBl, dA + 24576);
      gl_lds16((const char*)pBl + 65536, dA + 28672);
      pAh += 32; pAl += 32; pBh += 32; pBl += 32;
      __syncthreads();

      s16x8 ah[4], al[4], bh[4], bl[4];
#pragma unroll
      for (int m = 0; m < 4; ++m) {
        const int off = (wr * 64 + m * 16 + fr) * 32 + sgx * 8;
        ah[m] = *(const s16x8*)(Ahi + off);
        al[m] = *(const s16x8*)(Ahi + 4096 + off);
      }
#pragma unroll
      for (int n = 0; n < 4; ++n) {
        const int off = (wc * 64 + n * 16 + fr) * 32 + sgx * 8;
        bh[n] = *(const s16x8*)(Ahi + 8192 + off);
        bl[n] = *(const s16x8*)(Ahi + 12288 + off);
      }
#pragma unroll
      for (int m = 0; m < 4; ++m)
#pragma unroll
        for (int n = 0; n < 4; ++n) {
          acc[m][n] = __builtin_amdgcn_mfma_f32_16x16x32_bf16(ah[m], bh[n], acc[m][n], 0, 0, 0);
          acc[m][n] = __builtin_amdgcn_mfma_f32_16x16x32_bf16(ah[m], bl[n], acc[m][n], 0, 0, 0);
          acc[m][n] = __builtin_amdgcn_mfma_f32_16x16x32_bf16(al[m], bh[n], acc[m][n], 0, 0, 0);
        }
      __syncthreads();
    }
    pAh -= 512; pAl -= 512;
    pBh += 65024; pBl += 65024;

#pragma unroll 1
    for (int h = 0; h < 2; ++h) {
      if (wc == h) {
#pragma unroll
        for (int m = 0; m < 4; ++m)
#pragma unroll
          for (int n = 0; n < 4; ++n) {
            const int cl = n * 16 + fr;
            const int gcol = ct + h * 64 + cl;
            const int rbase = wr * 64 + m * 16 + fq * 4;
#pragma unroll
            for (int j = 0; j < 4; ++j) {
              float d2 = fmaf(-2.0f, acc[m][n][j], sqr[m][j] + sqc[n]);
              if (row0 + rbase + j == gcol) d2 = INF;
              Dt[(rbase + j) * 66 + cl] = d2;
            }
          }
      }
      __syncthreads();
      {
        const int cb2 = ssub * 32;
        float kth = tv[KNN - 1];
#pragma unroll 1
        for (int c = 0; c < 32; ++c) {
          const float d2 = Dt[srow * 66 + cb2 + c];
          if (d2 < kth) {
            const int gi = ct + h * 64 + cb2 + c;
#pragma unroll
            for (int j = KNN - 1; j >= 1; --j) {
              const bool ja = (tv[j] > d2), jb = (tv[j - 1] > d2);
              const float nv = jb ? tv[j - 1] : (ja ? d2 : tv[j]);
              const int ni = jb ? ti[j - 1] : (ja ? gi : ti[j]);
              tv[j] = nv; ti[j] = ni;
            }
            if (tv[0] > d2) { tv[0] = d2; ti[0] = gi; }
            kth = tv[KNN - 1];
          }
        }
      }
      __syncthreads();
    }
  }

#pragma unroll
  for (int j = 0; j < KNN; ++j) {
    SV[srow * 30 + ssub * 15 + j] = tv[j];
    SI[srow * 30 + ssub * 15 + j] = ti[j];
  }
  __syncthreads();
  if (tid < 128) {
    const int grow = row0 + tid;
    const size_t pb = (((size_t)which * 4 + split) * N + grow) * KNN;
    int p0 = 0, p1 = 0;
#pragma unroll
    for (int j = 0; j < KNN; ++j) {
      const float v0 = (p0 < KNN) ? SV[tid * 30 + p0] : INF;
      const float v1 = (p1 < KNN) ? SV[tid * 30 + 15 + p1] : INF;
      const int i0 = (p0 < KNN) ? SI[tid * 30 + p0] : 0x7fffffff;
      const int i1 = (p1 < KNN) ? SI[tid * 30 + 15 + p1] : 0x7fffffff;
      const bool t0 = (v0 < v1) || (v0 == v1 && i0 < i1);
      const float dv = t0 ? v0 : v1;
      const int di = t0 ? i0 : i1;
      if (t0) ++p0; else ++p1;
      pval[pb + j] = (dv > 0.f) ? sqrtf(fmaxf(dv, 1e-24f)) : 0.f;
      pidx[pb + j] = di;
    }
  }
}

// ---------------------------------------------------------------- MED: 4-way merge
__global__ __launch_bounds__(256)
void k_merge(const float* __restrict__ pval, const int* __restrict__ pidx,
             float* __restrict__ knnd, int* __restrict__ knni)
{
  const int flat = blockIdx.x * 256 + threadIdx.x;
  const int which = flat >> 13, row = flat & (N - 1);
  const size_t b0 = (((size_t)which * 4 + 0) * N + row) * KNN;
  const size_t b1 = (((size_t)which * 4 + 1) * N + row) * KNN;
  const size_t b2 = (((size_t)which * 4 + 2) * N + row) * KNN;
  const size_t b3 = (((size_t)which * 4 + 3) * N + row) * KNN;
  float v0 = pval[b0], v1 = pval[b1], v2 = pval[b2], v3 = pval[b3];
  int i0 = pidx[b0], i1 = pidx[b1], i2 = pidx[b2], i3 = pidx[b3];
  int p0 = 0, p1 = 0, p2 = 0, p3 = 0;
  const size_t ob = ((size_t)which * N + row) * KNN;
#pragma unroll 1
  for (int j = 0; j < KNN; ++j) {
    const bool a01 = (v0 < v1) || (v0 == v1 && i0 < i1);
    const float va = a01 ? v0 : v1; const int ia = a01 ? i0 : i1;
    const bool a23 = (v2 < v3) || (v2 == v3 && i2 < i3);
    const float vb = a23 ? v2 : v3; const int ib = a23 ? i2 : i3;
    const bool ab = (va < vb) || (va == vb && ia < ib);
    knnd[ob + j] = ab ? va : vb;
    knni[ob + j] = ab ? ia : ib;
    if (ab) {
      if (a01) { ++p0; v0 = (p0 < KNN) ? pval[b0 + p0] : INF; i0 = (p0 < KNN) ? pidx[b0 + p0] : 0x7fffffff; }
      else     { ++p1; v1 = (p1 < KNN) ? pval[b1 + p1] : INF; i1 = (p1 < KNN) ? pidx[b1 + p1] : 0x7fffffff; }
    } else {
      if (a23) { ++p2; v2 = (p2 < KNN) ? pval[b2 + p2] : INF; i2 = (p2 < KNN) ? pidx[b2 + p2] : 0x7fffffff; }
      else     { ++p3; v3 = (p3 < KNN) ? pval[b3 + p3] : INF; i3 = (p3 < KNN) ? pidx[b3 + p3] : 0x7fffffff; }
    }
  }
}

// ---------------------------------------------------------------- fallback: f32 VALU gram KNN
__global__ __launch_bounds__(256)
void k_knn_fb(const float* __restrict__ Ecur, const float* __restrict__ Eref,
              const float* __restrict__ sqall,
              float* __restrict__ knnd, int* __restrict__ knni)
{
  const int which = blockIdx.y;
  const float* E = which ? Eref : Ecur;
  const float* sq = sqall + which * N;
  float* outd = knnd + (size_t)which * N * KNN;
  int* outi = knni + (size_t)which * N * KNN;
  const int row0 = blockIdx.x * RB;

  __shared__ float As[RB][KB + 1];
  __shared__ float Bs[KB][CB + 4];
  __shared__ float Dtf[RB][CB + 1];
  __shared__ float topv[RB][KNN];
  __shared__ int topi[RB][KNN];

  const int tid = threadIdx.x;
  const int tx = tid & 15, ty = tid >> 4;

  if (tid < RB) {
#pragma unroll
    for (int j = 0; j < KNN; ++j) { topv[tid][j] = INF; topi[tid][j] = -1; }
  }

  for (int ct = 0; ct < N; ct += CB) {
    float acc[2][4] = {{0.f,0.f,0.f,0.f},{0.f,0.f,0.f,0.f}};
    for (int kt = 0; kt < D; kt += KB) {
      __syncthreads();
      {
        int r = tid >> 3, c4 = (tid & 7) << 2;
        const float4 v = *(const float4*)&E[(size_t)(row0 + r) * D + kt + c4];
        As[r][c4+0] = v.x; As[r][c4+1] = v.y; As[r][c4+2] = v.z; As[r][c4+3] = v.w;
      }
      {
        int k = tid & 31, cbase = tid >> 5;
#pragma unroll
        for (int i = 0; i < 8; ++i) {
          int c = cbase + (i << 3);
          Bs[k][c] = E[(size_t)(ct + c) * D + kt + k];
        }
      }
      __syncthreads();
#pragma unroll
      for (int k = 0; k < KB; ++k) {
        float a0 = As[2*ty + 0][k], a1 = As[2*ty + 1][k];
        float4 b = *(const float4*)&Bs[k][tx << 2];
        acc[0][0] = fmaf(a0, b.x, acc[0][0]); acc[0][1] = fmaf(a0, b.y, acc[0][1]);
        acc[0][2] = fmaf(a0, b.z, acc[0][2]); acc[0][3] = fmaf(a0, b.w, acc[0][3]);
        acc[1][0] = fmaf(a1, b.x, acc[1][0]); acc[1][1] = fmaf(a1, b.y, acc[1][1]);
        acc[1][2] = fmaf(a1, b.z, acc[1][2]); acc[1][3] = fmaf(a1, b.w, acc[1][3]);
      }
    }
    {
      float sr0 = sq[row0 + 2*ty + 0], sr1 = sq[row0 + 2*ty + 1];
#pragma unroll
      for (int c = 0; c < 4; ++c) {
        int gc = ct + (tx << 2) + c;
        float scv = sq[gc];
        float d20 = sr0 + scv - 2.0f * acc[0][c];
        float d21 = sr1 + scv - 2.0f * acc[1][c];
        float d0 = (d20 > 0.0f) ? sqrtf(fmaxf(d20, 1e-24f)) : 0.0f;
        float d1 = (d21 > 0.0f) ? sqrtf(fmaxf(d21, 1e-24f)) : 0.0f;
        if (gc == row0 + 2*ty + 0) d0 = INF;
        if (gc == row0 + 2*ty + 1) d1 = INF;
        Dtf[2*ty + 0][(tx << 2) + c] = d0;
        Dtf[2*ty + 1][(tx << 2) + c] = d1;
      }
    }
    __syncthreads();
    if (tid < RB) {
      float kth = topv[tid][KNN-1];
      for (int c = 0; c < CB; ++c) {
        float d = Dtf[tid][c];
        if (d < kth) {
          int gi = ct + c;
          int j = KNN - 1;
          while (j > 0 && topv[tid][j-1] > d) {
            topv[tid][j] = topv[tid][j-1]; topi[tid][j] = topi[tid][j-1]; --j;
          }
          topv[tid][j] = d; topi[tid][j] = gi;
          kth = topv[tid][KNN-1];
        }
      }
    }
    __syncthreads();
  }
  if (tid < RB) {
    int gr = row0 + tid;
#pragma unroll
    for (int j = 0; j < KNN; ++j) {
      outd[(size_t)gr * KNN + j] = topv[tid][j];
      outi[(size_t)gr * KNN + j] = topi[tid][j];
    }
  }
}

// ---------------------------------------------------------------- fused angular (ref pass + curr diff pass)
__global__ __launch_bounds__(256)
void k_ang2(const float* __restrict__ Ecur, const float* __restrict__ Eref,
            const int* __restrict__ knni, float* __restrict__ angpart)
{
  __shared__ float v[KNN][D];
  __shared__ float e[D];
  __shared__ float invn[KNN];
  __shared__ float cref[NPAIR];
  __shared__ float wpart[4];

  const int i = blockIdx.x;
  const int tid = threadIdx.x;
  const int lane = tid & 63;
  const int w = tid >> 6;

  float acc = 0.f;

#pragma unroll 1
  for (int pass = 0; pass < 2; ++pass) {
    const float* E = pass ? Ecur : Eref;
    const int* idx = knni + ((size_t)(pass ? 0 : 1) * N + i) * KNN;

    if (tid < 128)
      ((float4*)e)[tid] = ((const float4*)(E + (size_t)i * D))[tid];
    __syncthreads();

    for (int j = w; j < KNN; j += 4) {
      const float* src = E + (size_t)idx[j] * D;
      const int base = lane * 8;
      float4 x0 = *(const float4*)(src + base);
      float4 x1 = *(const float4*)(src + base + 4);
      float4 e0 = *(const float4*)(&e[base]);
      float4 e1 = *(const float4*)(&e[base + 4]);
      float d0 = x0.x-e0.x, d1 = x0.y-e0.y, d2 = x0.z-e0.z, d3 = x0.w-e0.w;
      float d4 = x1.x-e1.x, d5 = x1.y-e1.y, d6 = x1.z-e1.z, d7 = x1.w-e1.w;
      v[j][base+0]=d0; v[j][base+1]=d1; v[j][base+2]=d2; v[j][base+3]=d3;
      v[j][base+4]=d4; v[j][base+5]=d5; v[j][base+6]=d6; v[j][base+7]=d7;
      float s = d0*d0 + d1*d1 + d2*d2 + d3*d3 + d4*d4 + d5*d5 + d6*d6 + d7*d7;
#pragma unroll
      for (int o = 32; o; o >>= 1) s += __shfl_xor(s, o);
      if (lane == 0) invn[j] = 1.0f / fmaxf(sqrtf(s), 1e-12f);
    }
    __syncthreads();

    for (int p = w; p < NPAIR; p += 4) {
      int a = 0, q = p, rem = KNN - 1;
      while (q >= rem) { q -= rem; ++a; --rem; }
      int b = a + 1 + q;
      const float* va = v[a];
      const float* vb = v[b];
      const int base = lane * 8;
      float4 A0 = *(const float4*)(va + base);
      float4 A1 = *(const float4*)(va + base + 4);
      float4 B0 = *(const float4*)(vb + base);
      float4 B1 = *(const float4*)(vb + base + 4);
      float s = A0.x*B0.x + A0.y*B0.y + A0.z*B0.z + A0.w*B0.w
              + A1.x*B1.x + A1.y*B1.y + A1.z*B1.z + A1.w*B1.w;
#pragma unroll
      for (int o = 32; o; o >>= 1) s += __shfl_xor(s, o);
      if (lane == 0) {
        float cosv = s * invn[a] * invn[b];
        if (pass == 0) cref[p] = cosv;
        else { float dd = cosv - cref[p]; acc = fmaf(dd, dd, acc); }
      }
    }
    __syncthreads();
  }

  if (lane == 0) wpart[w] = acc;
  __syncthreads();
  if (tid == 0) angpart[i] = (wpart[0] + wpart[1]) + (wpart[2] + wpart[3]);
}

// ---------------------------------------------------------------- per-row stats
__global__ __launch_bounds__(256)
void k_stats(const float* __restrict__ knnd, float* __restrict__ dens,
             float* __restrict__ loss1part)
{
  __shared__ float red[256];
  int n = blockIdx.x * 256 + threadIdx.x;
  const float* dc = knnd + (size_t)n * KNN;
  const float* dr = knnd + (size_t)(N + n) * KNN;
  float mc = 0.f, mr = 0.f;
#pragma unroll
  for (int j = 0; j < KNN; ++j) { mc += dc[j]; mr += dr[j]; }
  mc *= (1.0f / KNN); mr *= (1.0f / KNN);
  float ic = 1.0f / (mc + EPSF);
  float ir = 1.0f / (mr + EPSF);
  float s = 0.f;
#pragma unroll
  for (int j = 0; j < KNN; ++j) {
    float t = dc[j] * ic - dr[j] * ir;
    s = fmaf(t, t, s);
  }
  dens[n] = ic;
  dens[N + n] = ir;
  red[threadIdx.x] = s;
  __syncthreads();
  for (int o = 128; o; o >>= 1) {
    if (threadIdx.x < o) red[threadIdx.x] += red[threadIdx.x + o];
    __syncthreads();
  }
  if (threadIdx.x == 0) loss1part[blockIdx.x] = red[0];
}

// ---------------------------------------------------------------- final combine
__global__ __launch_bounds__(256)
void k_final(const float* __restrict__ loss1part, const float* __restrict__ dens,
             const float* __restrict__ angpart, float* __restrict__ out)
{
  __shared__ float red[256];
  const int t = threadIdx.x;

  float sc = 0.f, sr = 0.f;
  for (int n = t; n < N; n += 256) { sc += dens[n]; sr += dens[N + n]; }
  red[t] = sc; __syncthreads();
  for (int o = 128; o; o >>= 1) { if (t < o) red[t] += red[t + o]; __syncthreads(); }
  float scm = red[0]; __syncthreads();
  red[t] = sr; __syncthreads();
  for (int o = 128; o; o >>= 1) { if (t < o) red[t] += red[t + o]; __syncthreads(); }
  float srm = red[0]; __syncthreads();

  float icm = 1.0f / (scm / (float)N + EPSF);
  float irm = 1.0f / (srm / (float)N + EPSF);

  float l2 = 0.f;
  for (int n = t; n < N; n += 256) {
    float dd = dens[n] * icm - dens[N + n] * irm;
    l2 = fmaf(dd, dd, l2);
  }
  red[t] = l2; __syncthreads();
  for (int o = 128; o; o >>= 1) { if (t < o) red[t] += red[t + o]; __syncthreads(); }
  float l2sum = red[0]; __syncthreads();

  float l1 = (t < 32) ? loss1part[t] : 0.f;
  red[t] = l1; __syncthreads();
  for (int o = 128; o; o >>= 1) { if (t < o) red[t] += red[t + o]; __syncthreads(); }
  float l1sum = red[0]; __syncthreads();

  float l3 = 0.f;
  for (int n = t; n < N; n += 256) l3 += angpart[n];
  red[t] = l3; __syncthreads();
  for (int o = 128; o; o >>= 1) { if (t < o) red[t] += red[t + o]; __syncthreads(); }
  float l3sum = red[0];

  if (t == 0) {
    out[0] = l1sum / (float)(N * KNN)
           + 0.5f * l2sum / (float)N
           + 0.5f * l3sum / (float)(N * NPAIR);
  }
}

// ---------------------------------------------------------------- launch
extern "C" void kernel_launch(void* const* d_in, const int* in_sizes, int n_in,
                              void* d_out, int out_size, void* d_ws, size_t ws_size,
                              hipStream_t stream)
{
  const float* emb = (const float*)d_in[0];
  const float* ref = (const float*)d_in[1];
  float* out = (float*)d_out;
  char* ws = (char*)d_ws;

  const size_t off_sq = 0;                                  // 2N f32
  const size_t off_hi = off_sq + (size_t)2 * N * 4;         // 2ND bf16
  const size_t off_lo = off_hi + (size_t)2 * N * D * 2;     // 2ND bf16

  // ---- SYM layout (pbuf reused per matrix)
  const size_t s_off_pb   = off_lo + (size_t)2 * N * D * 2;        // N*64*15 u64
  const size_t s_off_knnd = s_off_pb + (size_t)N * 64 * KNN * 8;
  const size_t s_off_knni = s_off_knnd + (size_t)2 * N * KNN * 4;
  const size_t s_off_angp = s_off_knni + (size_t)2 * N * KNN * 4;
  const size_t s_off_dens = s_off_angp + (size_t)N * 4;
  const size_t s_off_l1   = s_off_dens + (size_t)2 * N * 4;
  const size_t NEED_SYM   = s_off_l1 + 4096;

  // ---- MED layout
  const size_t m_off_pval = off_lo + (size_t)2 * N * D * 2;
  const size_t m_off_pidx = m_off_pval + (size_t)2 * 4 * N * KNN * 4;
  const size_t m_off_knnd = m_off_pidx + (size_t)2 * 4 * N * KNN * 4;
  const size_t m_off_knni = m_off_knnd + (size_t)2 * N * KNN * 4;
  const size_t m_off_angp = m_off_knni + (size_t)2 * N * KNN * 4;
  const size_t m_off_dens = m_off_angp + (size_t)N * 4;
  const size_t m_off_l1   = m_off_dens + (size_t)2 * N * 4;
  const size_t NEED_MED   = m_off_l1 + 4096;

  float* sq = (float*)(ws + off_sq);
  float* knnd; int* knni; float* angpart; float* dens; float* l1part;

  k_sqnorm<<<(2 * N) / 4, 256, 0, stream>>>(emb, ref, sq);

  if (ws_size >= NEED_SYM) {
    unsigned short* hi = (unsigned short*)(ws + off_hi);
    unsigned short* lo = (unsigned short*)(ws + off_lo);
    u64* pbuf = (u64*)(ws + s_off_pb);
    knnd = (float*)(ws + s_off_knnd);
    knni = (int*)(ws + s_off_knni);
    angpart = (float*)(ws + s_off_angp);
    dens = (float*)(ws + s_off_dens);
    l1part = (float*)(ws + s_off_l1);

    k_split<<<(2 * N * D / 8) / 256, 256, 0, stream>>>(emb, ref, hi, lo);
    for (int m = 0; m < 2; ++m) {
      k_sym<<<dim3(N / 128, N / 128), 256, 0, stream>>>(hi, lo, sq, pbuf, m);
      k_merge64<<<N / 4, 256, 0, stream>>>(pbuf, knnd, knni, m);
    }
  } else if (ws_size >= NEED_MED) {
    unsigned short* hi = (unsigned short*)(ws + off_hi);
    unsigned short* lo = (unsigned short*)(ws + off_lo);
    float* pval = (float*)(ws + m_off_pval);
    int* pidx = (int*)(ws + m_off_pidx);
    knnd = (float*)(ws + m_off_knnd);
    knni = (int*)(ws + m_off_knni);
    angpart = (float*)(ws + m_off_angp);
    dens = (float*)(ws + m_off_dens);
    l1part = (float*)(ws + m_off_l1);

    k_split<<<(2 * N * D / 8) / 256, 256, 0, stream>>>(emb, ref, hi, lo);
    k_med<<<dim3(N / 128, 4, 2), 256, 0, stream>>>(hi, lo, sq, pval, pidx);
    k_merge<<<(2 * N) / 256, 256, 0, stream>>>(pval, pidx, knnd, knni);
  } else {
    size_t o = off_hi;
    knnd = (float*)(ws + o); o += (size_t)2 * N * KNN * 4;
    knni = (int*)(ws + o);   o += (size_t)2 * N * KNN * 4;
    angpart = (float*)(ws + o); o += (size_t)N * 4;
    dens = (float*)(ws + o); o += (size_t)2 * N * 4;
    l1part = (float*)(ws + o);
    k_knn_fb<<<dim3(N / RB, 2), 256, 0, stream>>>(emb, ref, sq, knnd, knni);
  }

  k_ang2<<<N, 256, 0, stream>>>(emb, ref, knni, angpart);
  k_stats<<<N / 256, 256, 0, stream>>>(knnd, dens, l1part);
  k_final<<<1, 256, 0, stream>>>(l1part, dens, angpart, out);
}

// Round 5
// 1129.184 us; speedup vs baseline: 1.8773x; 1.8773x over previous
//
#include <hip/hip_runtime.h>

#define N 8192
#define D 512
#define KNN 15
#define NPAIR 105
#define EPSF 1e-8f

#define RB 32
#define CB 64
#define KB 32

#define INF __int_as_float(0x7f800000)

typedef __attribute__((ext_vector_type(4))) float f32x4;
typedef __attribute__((ext_vector_type(8))) short s16x8;
typedef __attribute__((ext_vector_type(8))) unsigned short u16x8;
typedef unsigned long long u64;

typedef const unsigned int __attribute__((address_space(1)))* gp_t;
typedef unsigned int __attribute__((address_space(3)))* lp_t;

__device__ __forceinline__ void gl_lds16(const void* g, void* l) {
  __builtin_amdgcn_global_load_lds((gp_t)g, (lp_t)l, 16, 0, 0);
}

__device__ __forceinline__ unsigned short bf16_rne(float x) {
  unsigned int u = __float_as_uint(x);
  return (unsigned short)((u + 0x7fffu + ((u >> 16) & 1u)) >> 16);
}

#define VMCNT8 asm volatile("s_waitcnt vmcnt(8)" ::: "memory")
#define VMCNT0 asm volatile("s_waitcnt vmcnt(0)" ::: "memory")
#define LGKM0  asm volatile("s_waitcnt lgkmcnt(0)" ::: "memory")
#define CFENCE asm volatile("" ::: "memory")

// ---------------------------------------------------------------- sq norms
__global__ __launch_bounds__(256)
void k_sqnorm(const float* __restrict__ A, const float* __restrict__ B,
              float* __restrict__ sq)
{
  int tid = threadIdx.x;
  int lane = tid & 63;
  int row = blockIdx.x * 4 + (tid >> 6);          // 0 .. 2N-1
  const float* src = (row < N) ? (A + (size_t)row * D)
                               : (B + (size_t)(row - N) * D);
  const float4* s4 = (const float4*)src + lane * 2;
  float4 x0 = s4[0], x1 = s4[1];
  float s = x0.x*x0.x + x0.y*x0.y + x0.z*x0.z + x0.w*x0.w
          + x1.x*x1.x + x1.y*x1.y + x1.z*x1.z + x1.w*x1.w;
#pragma unroll
  for (int o = 32; o; o >>= 1) s += __shfl_xor(s, o);
  if (lane == 0) sq[row] = s;
}

// ---------------------------------------------------------------- bf16 hi/lo split
__global__ __launch_bounds__(256)
void k_split(const float* __restrict__ A, const float* __restrict__ B,
             unsigned short* __restrict__ hi, unsigned short* __restrict__ lo)
{
  size_t t = (size_t)blockIdx.x * 256 + threadIdx.x;
  size_t base = t * 8;
  const float* src = (base < (size_t)N * D) ? (A + base) : (B + (base - (size_t)N * D));
  float4 x0 = ((const float4*)src)[0];
  float4 x1 = ((const float4*)src)[1];
  float xs[8] = {x0.x, x0.y, x0.z, x0.w, x1.x, x1.y, x1.z, x1.w};
  u16x8 hv, lv;
#pragma unroll
  for (int j = 0; j < 8; ++j) {
    unsigned short h = bf16_rne(xs[j]);
    float hf = __uint_as_float(((unsigned int)h) << 16);
    hv[j] = h;
    lv[j] = bf16_rne(xs[j] - hf);
  }
  *(u16x8*)(hi + base) = hv;
  *(u16x8*)(lo + base) = lv;
}

// ================================================================ MED path:
// fused MFMA gram + top-15, double-buffered staging with counted vmcnt.
// LDS: two 32KB stage buffers (buf sel at sel*32768):
//   Ahi [0,8K) Alo [8K,16K) Bhi [16K,24K) Blo [24K,32K), each [128 rows][64B]
// Epilogue overlays: Dt [128][65] f32, SV [128][30] f32 + SI [128][30] i32.
__global__ __launch_bounds__(256, 2)
void k_med(const unsigned short* __restrict__ hi, const unsigned short* __restrict__ lo,
           const float* __restrict__ sqall,
           float* __restrict__ pval, int* __restrict__ pidx)
{
  __shared__ __align__(16) char smem[65536];
  float* Dt = (float*)smem;
  float* SV = (float*)smem;
  int*   SI = (int*)(smem + 15360);

  const int tid = threadIdx.x;
  const int lane = tid & 63, w = tid >> 6;
  const int wr = w >> 1, wc = w & 1;
  const int fr = lane & 15, fq = lane >> 4;
  const int sgx = fq ^ ((fr >> 1) & 3);     // read-side seg swizzle (row-indep: (row>>1)&3 == (fr>>1)&3)

  const int rb = blockIdx.x, split = blockIdx.y, which = blockIdx.z;
  const int row0 = rb * 128;
  const int c0 = split * 2048;
  const size_t mbase = (size_t)which * N * D;
  const unsigned short* Hi = hi + mbase;
  const unsigned short* Lo = lo + mbase;
  const float* sq = sqall + which * N;

  // staging: thread -> (row sr_, seg sseg); source seg pre-swizzled so LDS stays linear
  const int sr_ = tid >> 2, sseg = tid & 3;
  const int ssg = sseg ^ ((sr_ >> 1) & 3);
  const unsigned short* pAh = Hi + (size_t)(row0 + sr_) * D + ssg * 8;
  const unsigned short* pAl = Lo + (size_t)(row0 + sr_) * D + ssg * 8;
  const unsigned short* pBh = Hi + (size_t)(c0 + sr_) * D + ssg * 8;
  const unsigned short* pBl = Lo + (size_t)(c0 + sr_) * D + ssg * 8;

  auto stage = [&](int sel) {
    char* d = smem + (sel << 15) + (w << 10);   // wave-uniform dest base
    gl_lds16(pAh, d);
    gl_lds16(pAh + 32768, d + 4096);            // rows +64 (+65536 B in global)
    gl_lds16(pAl, d + 8192);
    gl_lds16(pAl + 32768, d + 12288);
    gl_lds16(pBh, d + 16384);
    gl_lds16(pBh + 32768, d + 20480);
    gl_lds16(pBl, d + 24576);
    gl_lds16(pBl + 32768, d + 28672);
    pAh += 32; pAl += 32; pBh += 32; pBl += 32; // next K-step
  };

  const int srow = tid >> 1, ssub = tid & 1;
  float tv[KNN]; int ti[KNN];
#pragma unroll
  for (int j = 0; j < KNN; ++j) { tv[j] = INF; ti[j] = -1; }

  float sqr[4][4];
#pragma unroll
  for (int m = 0; m < 4; ++m)
#pragma unroll
    for (int j = 0; j < 4; ++j)
      sqr[m][j] = sq[row0 + wr * 64 + m * 16 + fq * 4 + j];

#pragma unroll 1
  for (int t = 0; t < 16; ++t) {
    const int ct = c0 + t * 128;
    float sqc[4];
#pragma unroll
    for (int n = 0; n < 4; ++n) sqc[n] = sq[ct + wc * 64 + n * 16 + fr];

    f32x4 acc[4][4];
#pragma unroll
    for (int m = 0; m < 4; ++m)
#pragma unroll
      for (int n = 0; n < 4; ++n) acc[m][n] = (f32x4){0.f, 0.f, 0.f, 0.f};

    // prologue: stage kt=0 into buf0 (safe: previous epilogue ended with __syncthreads)
    stage(0);
    int cur = 0;
#pragma unroll 1
    for (int kt = 0; kt < 16; ++kt) {
      if (kt < 15) {
        stage(cur ^ 1);   // 16 outstanding now
        VMCNT8;           // wait own 8 oldest = buf[cur] loads complete
      } else {
        VMCNT0;           // last step: drain remaining 8
      }
      __builtin_amdgcn_s_barrier();   // all waves' buf[cur] writes landed
      CFENCE;                         // pin ds_reads after the barrier

      const short* Sb = (const short*)(smem + (cur << 15));
      s16x8 ah[4], al[4], bh[4], bl[4];
#pragma unroll
      for (int m = 0; m < 4; ++m) {
        const int off = (wr * 64 + m * 16 + fr) * 32 + sgx * 8;
        ah[m] = *(const s16x8*)(Sb + off);
        al[m] = *(const s16x8*)(Sb + 4096 + off);
      }
#pragma unroll
      for (int n = 0; n < 4; ++n) {
        const int off = (wc * 64 + n * 16 + fr) * 32 + sgx * 8;
        bh[n] = *(const s16x8*)(Sb + 8192 + off);
        bl[n] = *(const s16x8*)(Sb + 12288 + off);
      }
#pragma unroll
      for (int m = 0; m < 4; ++m)
#pragma unroll
        for (int n = 0; n < 4; ++n) {
          acc[m][n] = __builtin_amdgcn_mfma_f32_16x16x32_bf16(ah[m], bh[n], acc[m][n], 0, 0, 0);
          acc[m][n] = __builtin_amdgcn_mfma_f32_16x16x32_bf16(ah[m], bl[n], acc[m][n], 0, 0, 0);
          acc[m][n] = __builtin_amdgcn_mfma_f32_16x16x32_bf16(al[m], bh[n], acc[m][n], 0, 0, 0);
        }

      LGKM0;                          // all ds_reads of buf[cur] serviced
      __builtin_amdgcn_s_barrier();   // no wave still reads buf[cur]
      CFENCE;                         // pin next stage() after the barrier
      cur ^= 1;
    }
    // pointers advanced 16*32 shorts; rewind A, advance B to next 128-col tile
    pAh -= 512; pAl -= 512;
    pBh += 65024; pBl += 65024;

    // ---- epilogue: distances + per-row scan (stage buffers dead, vmcnt drained)
#pragma unroll 1
    for (int h = 0; h < 2; ++h) {
      if (wc == h) {
#pragma unroll
        for (int m = 0; m < 4; ++m)
#pragma unroll
          for (int n = 0; n < 4; ++n) {
            const int cl = n * 16 + fr;
            const int gcol = ct + h * 64 + cl;
            const int rbase = wr * 64 + m * 16 + fq * 4;
#pragma unroll
            for (int j = 0; j < 4; ++j) {
              float d2 = fmaf(-2.0f, acc[m][n][j], sqr[m][j] + sqc[n]);
              if (row0 + rbase + j == gcol) d2 = INF;
              Dt[(rbase + j) * 65 + cl] = d2;
            }
          }
      }
      __syncthreads();
      {
        const int cb2 = ssub * 32;
        float kth = tv[KNN - 1];
#pragma unroll 1
        for (int c = 0; c < 32; ++c) {
          const float d2 = Dt[srow * 65 + cb2 + c];
          if (d2 < kth) {
            const int gi = ct + h * 64 + cb2 + c;
#pragma unroll
            for (int j = KNN - 1; j >= 1; --j) {
              const bool ja = (tv[j] > d2), jb = (tv[j - 1] > d2);
              const float nv = jb ? tv[j - 1] : (ja ? d2 : tv[j]);
              const int ni = jb ? ti[j - 1] : (ja ? gi : ti[j]);
              tv[j] = nv; ti[j] = ni;
            }
            if (tv[0] > d2) { tv[0] = d2; ti[0] = gi; }
            kth = tv[KNN - 1];
          }
        }
      }
      __syncthreads();
    }
  }

  // ---- block end: merge the 2 scanner lists per row, write partials
#pragma unroll
  for (int j = 0; j < KNN; ++j) {
    SV[srow * 30 + ssub * 15 + j] = tv[j];
    SI[srow * 30 + ssub * 15 + j] = ti[j];
  }
  __syncthreads();
  if (tid < 128) {
    const int grow = row0 + tid;
    const size_t pb = (((size_t)which * 4 + split) * N + grow) * KNN;
    int p0 = 0, p1 = 0;
#pragma unroll
    for (int j = 0; j < KNN; ++j) {
      const float v0 = (p0 < KNN) ? SV[tid * 30 + p0] : INF;
      const float v1 = (p1 < KNN) ? SV[tid * 30 + 15 + p1] : INF;
      const int i0 = (p0 < KNN) ? SI[tid * 30 + p0] : 0x7fffffff;
      const int i1 = (p1 < KNN) ? SI[tid * 30 + 15 + p1] : 0x7fffffff;
      const bool t0 = (v0 < v1) || (v0 == v1 && i0 < i1);
      const float dv = t0 ? v0 : v1;
      const int di = t0 ? i0 : i1;
      if (t0) ++p0; else ++p1;
      pval[pb + j] = (dv > 0.f) ? sqrtf(fmaxf(dv, 1e-24f)) : 0.f;
      pidx[pb + j] = di;
    }
  }
}

// ---------------------------------------------------------------- 4-way merge of split partials
__global__ __launch_bounds__(256)
void k_merge(const float* __restrict__ pval, const int* __restrict__ pidx,
             float* __restrict__ knnd, int* __restrict__ knni)
{
  const int flat = blockIdx.x * 256 + threadIdx.x;
  const int which = flat >> 13, row = flat & (N - 1);
  const size_t b0 = (((size_t)which * 4 + 0) * N + row) * KNN;
  const size_t b1 = (((size_t)which * 4 + 1) * N + row) * KNN;
  const size_t b2 = (((size_t)which * 4 + 2) * N + row) * KNN;
  const size_t b3 = (((size_t)which * 4 + 3) * N + row) * KNN;
  float v0 = pval[b0], v1 = pval[b1], v2 = pval[b2], v3 = pval[b3];
  int i0 = pidx[b0], i1 = pidx[b1], i2 = pidx[b2], i3 = pidx[b3];
  int p0 = 0, p1 = 0, p2 = 0, p3 = 0;
  const size_t ob = ((size_t)which * N + row) * KNN;
#pragma unroll 1
  for (int j = 0; j < KNN; ++j) {
    const bool a01 = (v0 < v1) || (v0 == v1 && i0 < i1);
    const float va = a01 ? v0 : v1; const int ia = a01 ? i0 : i1;
    const bool a23 = (v2 < v3) || (v2 == v3 && i2 < i3);
    const float vb = a23 ? v2 : v3; const int ib = a23 ? i2 : i3;
    const bool ab = (va < vb) || (va == vb && ia < ib);
    knnd[ob + j] = ab ? va : vb;
    knni[ob + j] = ab ? ia : ib;
    if (ab) {
      if (a01) { ++p0; v0 = (p0 < KNN) ? pval[b0 + p0] : INF; i0 = (p0 < KNN) ? pidx[b0 + p0] : 0x7fffffff; }
      else     { ++p1; v1 = (p1 < KNN) ? pval[b1 + p1] : INF; i1 = (p1 < KNN) ? pidx[b1 + p1] : 0x7fffffff; }
    } else {
      if (a23) { ++p2; v2 = (p2 < KNN) ? pval[b2 + p2] : INF; i2 = (p2 < KNN) ? pidx[b2 + p2] : 0x7fffffff; }
      else     { ++p3; v3 = (p3 < KNN) ? pval[b3 + p3] : INF; i3 = (p3 < KNN) ? pidx[b3 + p3] : 0x7fffffff; }
    }
  }
}

// ---------------------------------------------------------------- fallback: f32 VALU gram KNN
__global__ __launch_bounds__(256)
void k_knn_fb(const float* __restrict__ Ecur, const float* __restrict__ Eref,
              const float* __restrict__ sqall,
              float* __restrict__ knnd, int* __restrict__ knni)
{
  const int which = blockIdx.y;
  const float* E = which ? Eref : Ecur;
  const float* sq = sqall + which * N;
  float* outd = knnd + (size_t)which * N * KNN;
  int* outi = knni + (size_t)which * N * KNN;
  const int row0 = blockIdx.x * RB;

  __shared__ float As[RB][KB + 1];
  __shared__ float Bs[KB][CB + 4];
  __shared__ float Dtf[RB][CB + 1];
  __shared__ float topv[RB][KNN];
  __shared__ int topi[RB][KNN];

  const int tid = threadIdx.x;
  const int tx = tid & 15, ty = tid >> 4;

  if (tid < RB) {
#pragma unroll
    for (int j = 0; j < KNN; ++j) { topv[tid][j] = INF; topi[tid][j] = -1; }
  }

  for (int ct = 0; ct < N; ct += CB) {
    float acc[2][4] = {{0.f,0.f,0.f,0.f},{0.f,0.f,0.f,0.f}};
    for (int kt = 0; kt < D; kt += KB) {
      __syncthreads();
      {
        int r = tid >> 3, c4 = (tid & 7) << 2;
        const float4 v = *(const float4*)&E[(size_t)(row0 + r) * D + kt + c4];
        As[r][c4+0] = v.x; As[r][c4+1] = v.y; As[r][c4+2] = v.z; As[r][c4+3] = v.w;
      }
      {
        int k = tid & 31, cbase = tid >> 5;
#pragma unroll
        for (int i = 0; i < 8; ++i) {
          int c = cbase + (i << 3);
          Bs[k][c] = E[(size_t)(ct + c) * D + kt + k];
        }
      }
      __syncthreads();
#pragma unroll
      for (int k = 0; k < KB; ++k) {
        float a0 = As[2*ty + 0][k], a1 = As[2*ty + 1][k];
        float4 b = *(const float4*)&Bs[k][tx << 2];
        acc[0][0] = fmaf(a0, b.x, acc[0][0]); acc[0][1] = fmaf(a0, b.y, acc[0][1]);
        acc[0][2] = fmaf(a0, b.z, acc[0][2]); acc[0][3] = fmaf(a0, b.w, acc[0][3]);
        acc[1][0] = fmaf(a1, b.x, acc[1][0]); acc[1][1] = fmaf(a1, b.y, acc[1][1]);
        acc[1][2] = fmaf(a1, b.z, acc[1][2]); acc[1][3] = fmaf(a1, b.w, acc[1][3]);
      }
    }
    {
      float sr0 = sq[row0 + 2*ty + 0], sr1 = sq[row0 + 2*ty + 1];
#pragma unroll
      for (int c = 0; c < 4; ++c) {
        int gc = ct + (tx << 2) + c;
        float scv = sq[gc];
        float d20 = sr0 + scv - 2.0f * acc[0][c];
        float d21 = sr1 + scv - 2.0f * acc[1][c];
        float d0 = (d20 > 0.0f) ? sqrtf(fmaxf(d20, 1e-24f)) : 0.0f;
        float d1 = (d21 > 0.0f) ? sqrtf(fmaxf(d21, 1e-24f)) : 0.0f;
        if (gc == row0 + 2*ty + 0) d0 = INF;
        if (gc == row0 + 2*ty + 1) d1 = INF;
        Dtf[2*ty + 0][(tx << 2) + c] = d0;
        Dtf[2*ty + 1][(tx << 2) + c] = d1;
      }
    }
    __syncthreads();
    if (tid < RB) {
      float kth = topv[tid][KNN-1];
      for (int c = 0; c < CB; ++c) {
        float d = Dtf[tid][c];
        if (d < kth) {
          int gi = ct + c;
          int j = KNN - 1;
          while (j > 0 && topv[tid][j-1] > d) {
            topv[tid][j] = topv[tid][j-1]; topi[tid][j] = topi[tid][j-1]; --j;
          }
          topv[tid][j] = d; topi[tid][j] = gi;
          kth = topv[tid][KNN-1];
        }
      }
    }
    __syncthreads();
  }
  if (tid < RB) {
    int gr = row0 + tid;
#pragma unroll
    for (int j = 0; j < KNN; ++j) {
      outd[(size_t)gr * KNN + j] = topv[tid][j];
      outi[(size_t)gr * KNN + j] = topi[tid][j];
    }
  }
}

// ---------------------------------------------------------------- fused angular (ref pass + curr diff pass)
__global__ __launch_bounds__(256)
void k_ang2(const float* __restrict__ Ecur, const float* __restrict__ Eref,
            const int* __restrict__ knni, float* __restrict__ angpart)
{
  __shared__ float v[KNN][D];
  __shared__ float e[D];
  __shared__ float invn[KNN];
  __shared__ float cref[NPAIR];
  __shared__ float wpart[4];

  const int i = blockIdx.x;
  const int tid = threadIdx.x;
  const int lane = tid & 63;
  const int w = tid >> 6;

  float acc = 0.f;

#pragma unroll 1
  for (int pass = 0; pass < 2; ++pass) {
    const float* E = pass ? Ecur : Eref;
    const int* idx = knni + ((size_t)(pass ? 0 : 1) * N + i) * KNN;

    if (tid < 128)
      ((float4*)e)[tid] = ((const float4*)(E + (size_t)i * D))[tid];
    __syncthreads();

    for (int j = w; j < KNN; j += 4) {
      const float* src = E + (size_t)idx[j] * D;
      const int base = lane * 8;
      float4 x0 = *(const float4*)(src + base);
      float4 x1 = *(const float4*)(src + base + 4);
      float4 e0 = *(const float4*)(&e[base]);
      float4 e1 = *(const float4*)(&e[base + 4]);
      float d0 = x0.x-e0.x, d1 = x0.y-e0.y, d2 = x0.z-e0.z, d3 = x0.w-e0.w;
      float d4 = x1.x-e1.x, d5 = x1.y-e1.y, d6 = x1.z-e1.z, d7 = x1.w-e1.w;
      v[j][base+0]=d0; v[j][base+1]=d1; v[j][base+2]=d2; v[j][base+3]=d3;
      v[j][base+4]=d4; v[j][base+5]=d5; v[j][base+6]=d6; v[j][base+7]=d7;
      float s = d0*d0 + d1*d1 + d2*d2 + d3*d3 + d4*d4 + d5*d5 + d6*d6 + d7*d7;
#pragma unroll
      for (int o = 32; o; o >>= 1) s += __shfl_xor(s, o);
      if (lane == 0) invn[j] = 1.0f / fmaxf(sqrtf(s), 1e-12f);
    }
    __syncthreads();

    for (int p = w; p < NPAIR; p += 4) {
      int a = 0, q = p, rem = KNN - 1;
      while (q >= rem) { q -= rem; ++a; --rem; }
      int b = a + 1 + q;
      const float* va = v[a];
      const float* vb = v[b];
      const int base = lane * 8;
      float4 A0 = *(const float4*)(va + base);
      float4 A1 = *(const float4*)(va + base + 4);
      float4 B0 = *(const float4*)(vb + base);
      float4 B1 = *(const float4*)(vb + base + 4);
      float s = A0.x*B0.x + A0.y*B0.y + A0.z*B0.z + A0.w*B0.w
              + A1.x*B1.x + A1.y*B1.y + A1.z*B1.z + A1.w*B1.w;
#pragma unroll
      for (int o = 32; o; o >>= 1) s += __shfl_xor(s, o);
      if (lane == 0) {
        float cosv = s * invn[a] * invn[b];
        if (pass == 0) cref[p] = cosv;
        else { float dd = cosv - cref[p]; acc = fmaf(dd, dd, acc); }
      }
    }
    __syncthreads();
  }

  if (lane == 0) wpart[w] = acc;
  __syncthreads();
  if (tid == 0) angpart[i] = (wpart[0] + wpart[1]) + (wpart[2] + wpart[3]);
}

// ---------------------------------------------------------------- per-row stats
__global__ __launch_bounds__(256)
void k_stats(const float* __restrict__ knnd, float* __restrict__ dens,
             float* __restrict__ loss1part)
{
  __shared__ float red[256];
  int n = blockIdx.x * 256 + threadIdx.x;
  const float* dc = knnd + (size_t)n * KNN;
  const float* dr = knnd + (size_t)(N + n) * KNN;
  float mc = 0.f, mr = 0.f;
#pragma unroll
  for (int j = 0; j < KNN; ++j) { mc += dc[j]; mr += dr[j]; }
  mc *= (1.0f / KNN); mr *= (1.0f / KNN);
  float ic = 1.0f / (mc + EPSF);
  float ir = 1.0f / (mr + EPSF);
  float s = 0.f;
#pragma unroll
  for (int j = 0; j < KNN; ++j) {
    float t = dc[j] * ic - dr[j] * ir;
    s = fmaf(t, t, s);
  }
  dens[n] = ic;
  dens[N + n] = ir;
  red[threadIdx.x] = s;
  __syncthreads();
  for (int o = 128; o; o >>= 1) {
    if (threadIdx.x < o) red[threadIdx.x] += red[threadIdx.x + o];
    __syncthreads();
  }
  if (threadIdx.x == 0) loss1part[blockIdx.x] = red[0];
}

// ---------------------------------------------------------------- final combine
__global__ __launch_bounds__(256)
void k_final(const float* __restrict__ loss1part, const float* __restrict__ dens,
             const float* __restrict__ angpart, float* __restrict__ out)
{
  __shared__ float red[256];
  const int t = threadIdx.x;

  float sc = 0.f, sr = 0.f;
  for (int n = t; n < N; n += 256) { sc += dens[n]; sr += dens[N + n]; }
  red[t] = sc; __syncthreads();
  for (int o = 128; o; o >>= 1) { if (t < o) red[t] += red[t + o]; __syncthreads(); }
  float scm = red[0]; __syncthreads();
  red[t] = sr; __syncthreads();
  for (int o = 128; o; o >>= 1) { if (t < o) red[t] += red[t + o]; __syncthreads(); }
  float srm = red[0]; __syncthreads();

  float icm = 1.0f / (scm / (float)N + EPSF);
  float irm = 1.0f / (srm / (float)N + EPSF);

  float l2 = 0.f;
  for (int n = t; n < N; n += 256) {
    float dd = dens[n] * icm - dens[N + n] * irm;
    l2 = fmaf(dd, dd, l2);
  }
  red[t] = l2; __syncthreads();
  for (int o = 128; o; o >>= 1) { if (t < o) red[t] += red[t + o]; __syncthreads(); }
  float l2sum = red[0]; __syncthreads();

  float l1 = (t < 32) ? loss1part[t] : 0.f;
  red[t] = l1; __syncthreads();
  for (int o = 128; o; o >>= 1) { if (t < o) red[t] += red[t + o]; __syncthreads(); }
  float l1sum = red[0]; __syncthreads();

  float l3 = 0.f;
  for (int n = t; n < N; n += 256) l3 += angpart[n];
  red[t] = l3; __syncthreads();
  for (int o = 128; o; o >>= 1) { if (t < o) red[t] += red[t + o]; __syncthreads(); }
  float l3sum = red[0];

  if (t == 0) {
    out[0] = l1sum / (float)(N * KNN)
           + 0.5f * l2sum / (float)N
           + 0.5f * l3sum / (float)(N * NPAIR);
  }
}

// ---------------------------------------------------------------- launch
extern "C" void kernel_launch(void* const* d_in, const int* in_sizes, int n_in,
                              void* d_out, int out_size, void* d_ws, size_t ws_size,
                              hipStream_t stream)
{
  const float* emb = (const float*)d_in[0];
  const float* ref = (const float*)d_in[1];
  float* out = (float*)d_out;
  char* ws = (char*)d_ws;

  const size_t off_sq = 0;                                  // 2N f32
  const size_t off_hi = off_sq + (size_t)2 * N * 4;         // 2ND bf16
  const size_t off_lo = off_hi + (size_t)2 * N * D * 2;     // 2ND bf16

  // MED layout (~44 MB; ws known >= ~99 MB from R4's SYM path having run)
  const size_t m_off_pval = off_lo + (size_t)2 * N * D * 2;
  const size_t m_off_pidx = m_off_pval + (size_t)2 * 4 * N * KNN * 4;
  const size_t m_off_knnd = m_off_pidx + (size_t)2 * 4 * N * KNN * 4;
  const size_t m_off_knni = m_off_knnd + (size_t)2 * N * KNN * 4;
  const size_t m_off_angp = m_off_knni + (size_t)2 * N * KNN * 4;
  const size_t m_off_dens = m_off_angp + (size_t)N * 4;
  const size_t m_off_l1   = m_off_dens + (size_t)2 * N * 4;
  const size_t NEED_MED   = m_off_l1 + 4096;

  float* sq = (float*)(ws + off_sq);
  float* knnd; int* knni; float* angpart; float* dens; float* l1part;

  k_sqnorm<<<(2 * N) / 4, 256, 0, stream>>>(emb, ref, sq);

  if (ws_size >= NEED_MED) {
    unsigned short* hi = (unsigned short*)(ws + off_hi);
    unsigned short* lo = (unsigned short*)(ws + off_lo);
    float* pval = (float*)(ws + m_off_pval);
    int* pidx = (int*)(ws + m_off_pidx);
    knnd = (float*)(ws + m_off_knnd);
    knni = (int*)(ws + m_off_knni);
    angpart = (float*)(ws + m_off_angp);
    dens = (float*)(ws + m_off_dens);
    l1part = (float*)(ws + m_off_l1);

    k_split<<<(2 * N * D / 8) / 256, 256, 0, stream>>>(emb, ref, hi, lo);
    k_med<<<dim3(N / 128, 4, 2), 256, 0, stream>>>(hi, lo, sq, pval, pidx);
    k_merge<<<(2 * N) / 256, 256, 0, stream>>>(pval, pidx, knnd, knni);
  } else {
    size_t o = off_hi;
    knnd = (float*)(ws + o); o += (size_t)2 * N * KNN * 4;
    knni = (int*)(ws + o);   o += (size_t)2 * N * KNN * 4;
    angpart = (float*)(ws + o); o += (size_t)N * 4;
    dens = (float*)(ws + o); o += (size_t)2 * N * 4;
    l1part = (float*)(ws + o);
    k_knn_fb<<<dim3(N / RB, 2), 256, 0, stream>>>(emb, ref, sq, knnd, knni);
  }

  k_ang2<<<N, 256, 0, stream>>>(emb, ref, knni, angpart);
  k_stats<<<N / 256, 256, 0, stream>>>(knnd, dens, l1part);
  k_final<<<1, 256, 0, stream>>>(l1part, dens, angpart, out);
}